// Round 10
// baseline (311.910 us; speedup 1.0000x reference)
//
#include <hip/hip_runtime.h>

#define B_N    1024
#define F_DIMC 768
#define M_DIM  512
#define C_N    100
#define KHALF  (F_DIMC / 2)     // 384 per K-split half
#define NT2    (KHALF / 32)     // 12 k-steps of BK=32
#define NGEMM  512              // 256 tiles x 2 K-halves
#define NIDX   25               // 25 blocks x 4 waves = 100 classes
#define REP    8                // diagnostic repeat (idempotent re-writes)

typedef float f32x4 __attribute__((ext_vector_type(4)));

// ---------------------------------------------------------------------------
// Kernel 1: partial GEMM (K-split x2, no relu) + per-class index build.
// R8 structure, x REP idempotent repeats for counter visibility.
// ---------------------------------------------------------------------------
__global__ __launch_bounds__(256) void gemm_index_kernel(
    const float* __restrict__ X, const float* __restrict__ W,
    const int* __restrict__ labels, float* __restrict__ part,
    int* __restrict__ counts, int* __restrict__ idx) {
  __shared__ float As[2][32][36];  // k-major A tile
  __shared__ float Bs[2][32][64];
  __shared__ int   lab[B_N];

  const int t = threadIdx.x;

  if (blockIdx.x >= NGEMM) {  // ---- index path ----
    for (int i = t; i < B_N; i += 256) lab[i] = labels[i];
    __syncthreads();
    const int w    = t >> 6;
    const int lane = t & 63;
    const int c    = ((int)blockIdx.x - NGEMM) * 4 + w;
    for (int rep = 0; rep < REP; ++rep) {
      if (c < C_N) {
        int base = 0;
        for (int ch = 0; ch < 16; ++ch) {
          const int j = ch * 64 + lane;
          const bool hit = (lab[j] == c);
          const unsigned long long mask = __ballot(hit);
          if (hit) {
            const int r = __popcll(mask & ((1ull << lane) - 1ull));
            idx[c * B_N + base + r] = j;
          }
          base += __popcll(mask);
        }
        if (lane == 0) counts[c] = base;
      }
    }
    return;
  }

  // ---- GEMM path ----
  const int kb   = (int)blockIdx.x >> 8;        // K-half 0/1
  const int tile = (int)blockIdx.x & 255;
  const int bm = (tile >> 3) * 32;
  const int bn = (tile & 7) * 64;
  const int tx = t & 15;   // col group (x4) -> 64 cols
  const int ty = t >> 4;   // row group (x2) -> 32 rows

  const int ar  = t >> 3;        // A row 0..31
  const int akq = (t & 7) * 4;   // A k-quad
  const int bk0 = t >> 4;        // B k-rows
  const int bk1 = bk0 + 16;
  const int bnq = (t & 15) * 4;  // B col-quad

  const float* __restrict__ Arow =
      X + (size_t)(bm + ar) * F_DIMC + kb * KHALF + akq;
  const float* __restrict__ Bcol =
      W + (size_t)kb * KHALF * M_DIM + bn + bnq;

  for (int rep = 0; rep < REP; ++rep) {
    float4 pa  = *(const float4*)(Arow);
    float4 pb0 = *(const float4*)(Bcol + (size_t)bk0 * M_DIM);
    float4 pb1 = *(const float4*)(Bcol + (size_t)bk1 * M_DIM);

    float acc[2][4] = {};

    As[0][akq + 0][ar] = pa.x;
    As[0][akq + 1][ar] = pa.y;
    As[0][akq + 2][ar] = pa.z;
    As[0][akq + 3][ar] = pa.w;
    *(float4*)&Bs[0][bk0][bnq] = pb0;
    *(float4*)&Bs[0][bk1][bnq] = pb1;
    __syncthreads();

    for (int it = 0; it < NT2; ++it) {
      const int cur = it & 1;
      if (it + 1 < NT2) {
        const int k0 = (it + 1) * 32;
        pa  = *(const float4*)(Arow + k0);
        pb0 = *(const float4*)(Bcol + (size_t)(k0 + bk0) * M_DIM);
        pb1 = *(const float4*)(Bcol + (size_t)(k0 + bk1) * M_DIM);
      }
#pragma unroll
      for (int kk = 0; kk < 32; ++kk) {
        float2 av = *(const float2*)&As[cur][kk][ty * 2];
        float4 bv = *(const float4*)&Bs[cur][kk][tx * 4];
        acc[0][0] += av.x * bv.x;
        acc[0][1] += av.x * bv.y;
        acc[0][2] += av.x * bv.z;
        acc[0][3] += av.x * bv.w;
        acc[1][0] += av.y * bv.x;
        acc[1][1] += av.y * bv.y;
        acc[1][2] += av.y * bv.z;
        acc[1][3] += av.y * bv.w;
      }
      if (it + 1 < NT2) {
        const int nxt = cur ^ 1;
        As[nxt][akq + 0][ar] = pa.x;
        As[nxt][akq + 1][ar] = pa.y;
        As[nxt][akq + 2][ar] = pa.z;
        As[nxt][akq + 3][ar] = pa.w;
        *(float4*)&Bs[nxt][bk0][bnq] = pb0;
        *(float4*)&Bs[nxt][bk1][bnq] = pb1;
      }
      __syncthreads();
    }

    float* __restrict__ dst = part + (size_t)kb * B_N * M_DIM;
#pragma unroll
    for (int j = 0; j < 2; ++j) {
      float4 o = make_float4(acc[j][0], acc[j][1], acc[j][2], acc[j][3]);
      *(float4*)&dst[(size_t)(bm + ty * 2 + j) * M_DIM + bn + tx * 4] = o;
    }
    __syncthreads();  // LDS safe before next rep restages
  }
}

// ---------------------------------------------------------------------------
// Kernel 2: phi row-panels + mu/count (R8 structure), x REP repeats.
// grid = (17, C): panels 0..15 -> 32 rows x 512 cols; panel 16 -> mu/count.
// ---------------------------------------------------------------------------
__global__ __launch_bounds__(256, 4) void phi_mu_kernel(
    const float* __restrict__ p0, const float* __restrict__ p1,
    const int* __restrict__ counts, const int* __restrict__ idx,
    float* __restrict__ phi, float* __restrict__ mu,
    float* __restrict__ cnt_out) {
  const int c = blockIdx.y;
  const int n = counts[c];
  const int* __restrict__ id = idx + c * B_N;
  const int t = threadIdx.x;

  if (blockIdx.x == 16) {  // ---- mu / count path ----
    for (int rep = 0; rep < REP; ++rep) {
      float2 acc = make_float2(0.f, 0.f);
      for (int s = 0; s < n; ++s) {
        const size_t o = (size_t)id[s] * M_DIM + t * 2;
        const float2 q0 = *(const float2*)&p0[o];
        const float2 q1 = *(const float2*)&p1[o];
        acc.x += fmaxf(q0.x + q1.x, 0.f);
        acc.y += fmaxf(q0.y + q1.y, 0.f);
      }
      *(float2*)&mu[(size_t)c * M_DIM + t * 2] = acc;
      if (t == 0) cnt_out[c] = (float)n;
    }
    return;
  }

  // ---- phi row-panel path: rows 32*px..+32, all 512 cols ----
  const int px = (int)blockIdx.x;      // 0..15
  const int tr = t >> 6;               // row group 0..3 (x8 rows)
  const int tc = t & 63;               // col group: cols tc*4 and 256+tc*4

  __shared__ float F[16][M_DIM];

  for (int rep = 0; rep < REP; ++rep) {
    float acc[8][8] = {};

    for (int s0 = 0; s0 < n; s0 += 16) {
      const int chunk  = min(16, n - s0);
      if (s0 || rep) __syncthreads();  // protect F before overwrite
      const int nslots = chunk << 7;   // chunk * 128 float4 per row
      for (int v = t; v < nslots; v += 256) {
        const int sl   = v >> 7;
        const int fp   = (v & 127) << 2;
        const size_t o = (size_t)id[s0 + sl] * M_DIM + fp;
        const float4 q0 = *(const float4*)&p0[o];
        const float4 q1 = *(const float4*)&p1[o];
        float4 f;
        f.x = fmaxf(q0.x + q1.x, 0.f);
        f.y = fmaxf(q0.y + q1.y, 0.f);
        f.z = fmaxf(q0.z + q1.z, 0.f);
        f.w = fmaxf(q0.w + q1.w, 0.f);
        *(float4*)&F[sl][fp] = f;
      }
      __syncthreads();
      for (int sl = 0; sl < chunk; ++sl) {
        const float4 a0 = *(const float4*)&F[sl][px * 32 + tr * 8];
        const float4 a1 = *(const float4*)&F[sl][px * 32 + tr * 8 + 4];
        const float4 b0 = *(const float4*)&F[sl][tc * 4];
        const float4 b1 = *(const float4*)&F[sl][256 + tc * 4];
        const float av[8] = {a0.x, a0.y, a0.z, a0.w, a1.x, a1.y, a1.z, a1.w};
        const float bv[8] = {b0.x, b0.y, b0.z, b0.w, b1.x, b1.y, b1.z, b1.w};
#pragma unroll
        for (int r = 0; r < 8; ++r)
#pragma unroll
          for (int q = 0; q < 8; ++q)
            acc[r][q] += av[r] * bv[q];
      }
    }

    float* __restrict__ out = phi + (size_t)c * M_DIM * M_DIM;
#pragma unroll
    for (int r = 0; r < 8; ++r) {
      const size_t row = (size_t)(px * 32 + tr * 8 + r) * M_DIM;
      const f32x4 o0 = {acc[r][0], acc[r][1], acc[r][2], acc[r][3]};
      const f32x4 o1 = {acc[r][4], acc[r][5], acc[r][6], acc[r][7]};
      __builtin_nontemporal_store(o0, (f32x4*)&out[row + tc * 4]);
      __builtin_nontemporal_store(o1, (f32x4*)&out[row + 256 + tc * 4]);
    }
  }
}

// ---------------------------------------------------------------------------
extern "C" void kernel_launch(void* const* d_in, const int* in_sizes, int n_in,
                              void* d_out, int out_size, void* d_ws,
                              size_t ws_size, hipStream_t stream) {
  const float* X      = (const float*)d_in[0];
  const float* W      = (const float*)d_in[1];
  const int*   labels = (const int*)d_in[2];

  float* out = (float*)d_out;
  float* phi = out;                                // C*M*M
  float* mu  = out + (size_t)C_N * M_DIM * M_DIM;  // C*M
  float* cnt = mu + (size_t)C_N * M_DIM;           // C

  float* part   = (float*)d_ws;                    // 2 x B*M fp32 = 4 MB
  int*   counts = (int*)((char*)d_ws + (size_t)2 * B_N * M_DIM * sizeof(float));
  int*   idx    = counts + 128;                    // C*B ints

  hipLaunchKernelGGL(gemm_index_kernel, dim3(NGEMM + NIDX), dim3(256), 0,
                     stream, X, W, labels, part, counts, idx);
  hipLaunchKernelGGL(phi_mu_kernel, dim3(17, C_N), dim3(256), 0, stream,
                     part, part + (size_t)B_N * M_DIM, counts, idx,
                     phi, mu, cnt);
}

// Round 11
// 48.827 us; speedup vs baseline: 6.3880x; 6.3880x over previous
//
#include <hip/hip_runtime.h>

#define B_N    1024
#define F_DIMC 768
#define M_DIM  512
#define C_N    100
#define KSPLIT 4
#define KPER   (F_DIMC / KSPLIT)   // 192 per split
#define NBK    (KPER / 32)         // 6 BK-steps of 32
#define NGEMM  512                 // 128 tiles x 4 K-splits
#define NIDX   25                  // 25 blocks x 4 waves = 100 classes

// ---------------------------------------------------------------------------
// Kernel 1: partial GEMM (K-split x4, no relu, 4 separate buffers) +
// per-class index build.
// blocks 0..511: 64x64 tile, 4x4 acc/thread (av b128 + bv b128 per kk),
//   KPER=192 each, 256 thr, double-buffered LDS.
// blocks 512..536: one wave per class, ballot-based stable rank.
// ---------------------------------------------------------------------------
__global__ __launch_bounds__(256) void gemm_index_kernel(
    const float* __restrict__ X, const float* __restrict__ W,
    const int* __restrict__ labels, float* __restrict__ part,
    int* __restrict__ counts, int* __restrict__ idx) {
  __shared__ float As[2][32][68];  // k-major A tile (64 rows), pad 68
  __shared__ float Bs[2][32][64];
  __shared__ int   lab[B_N];

  const int t = threadIdx.x;

  if (blockIdx.x >= NGEMM) {  // ---- index path ----
    for (int i = t; i < B_N; i += 256) lab[i] = labels[i];
    __syncthreads();
    const int w    = t >> 6;
    const int lane = t & 63;
    const int c    = ((int)blockIdx.x - NGEMM) * 4 + w;
    if (c < C_N) {
      int base = 0;
      for (int ch = 0; ch < 16; ++ch) {
        const int j = ch * 64 + lane;
        const bool hit = (lab[j] == c);
        const unsigned long long mask = __ballot(hit);
        if (hit) {
          const int r = __popcll(mask & ((1ull << lane) - 1ull));
          idx[c * B_N + base + r] = j;
        }
        base += __popcll(mask);
      }
      if (lane == 0) counts[c] = base;
    }
    return;
  }

  // ---- GEMM path ----
  const int kb   = (int)blockIdx.x >> 7;   // K-split 0..3
  const int tile = (int)blockIdx.x & 127;  // 0..127
  const int bm = (tile >> 3) * 64;         // 16 row tiles
  const int bn = (tile & 7) * 64;          // 8 col tiles
  const int tr = t >> 4;                   // rows tr*4..+3
  const int tc = t & 15;                   // cols tc*4..+3

  // staging maps, two slots per thread: s0 = t, s1 = t + 256
  const int ar0 = t >> 3,          akq0 = (t & 7) * 4;
  const int ar1 = (t + 256) >> 3,  akq1 = (t & 7) * 4;   // (t+256)&7 == t&7
  const int bkr0 = t >> 4,         bnq0 = (t & 15) * 4;
  const int bkr1 = (t + 256) >> 4, bnq1 = (t & 15) * 4;

  const float* __restrict__ Xb = X + (size_t)bm * F_DIMC + kb * KPER;
  const float* __restrict__ Wb = W + (size_t)kb * KPER * M_DIM + bn;

  float4 pa0 = *(const float4*)&Xb[(size_t)ar0 * F_DIMC + akq0];
  float4 pa1 = *(const float4*)&Xb[(size_t)ar1 * F_DIMC + akq1];
  float4 pb0 = *(const float4*)&Wb[(size_t)bkr0 * M_DIM + bnq0];
  float4 pb1 = *(const float4*)&Wb[(size_t)bkr1 * M_DIM + bnq1];

  float acc[4][4] = {};

  As[0][akq0 + 0][ar0] = pa0.x;
  As[0][akq0 + 1][ar0] = pa0.y;
  As[0][akq0 + 2][ar0] = pa0.z;
  As[0][akq0 + 3][ar0] = pa0.w;
  As[0][akq1 + 0][ar1] = pa1.x;
  As[0][akq1 + 1][ar1] = pa1.y;
  As[0][akq1 + 2][ar1] = pa1.z;
  As[0][akq1 + 3][ar1] = pa1.w;
  *(float4*)&Bs[0][bkr0][bnq0] = pb0;
  *(float4*)&Bs[0][bkr1][bnq1] = pb1;
  __syncthreads();

  for (int it = 0; it < NBK; ++it) {
    const int cur = it & 1;
    if (it + 1 < NBK) {
      const int k0 = (it + 1) * 32;
      pa0 = *(const float4*)&Xb[(size_t)ar0 * F_DIMC + k0 + akq0];
      pa1 = *(const float4*)&Xb[(size_t)ar1 * F_DIMC + k0 + akq1];
      pb0 = *(const float4*)&Wb[(size_t)(k0 + bkr0) * M_DIM + bnq0];
      pb1 = *(const float4*)&Wb[(size_t)(k0 + bkr1) * M_DIM + bnq1];
    }
#pragma unroll
    for (int kk = 0; kk < 32; ++kk) {
      const float4 a = *(const float4*)&As[cur][kk][tr * 4];
      const float4 b = *(const float4*)&Bs[cur][kk][tc * 4];
      const float av[4] = {a.x, a.y, a.z, a.w};
      const float bv[4] = {b.x, b.y, b.z, b.w};
#pragma unroll
      for (int j = 0; j < 4; ++j)
#pragma unroll
        for (int q = 0; q < 4; ++q)
          acc[j][q] += av[j] * bv[q];
    }
    if (it + 1 < NBK) {
      const int nxt = cur ^ 1;
      As[nxt][akq0 + 0][ar0] = pa0.x;
      As[nxt][akq0 + 1][ar0] = pa0.y;
      As[nxt][akq0 + 2][ar0] = pa0.z;
      As[nxt][akq0 + 3][ar0] = pa0.w;
      As[nxt][akq1 + 0][ar1] = pa1.x;
      As[nxt][akq1 + 1][ar1] = pa1.y;
      As[nxt][akq1 + 2][ar1] = pa1.z;
      As[nxt][akq1 + 3][ar1] = pa1.w;
      *(float4*)&Bs[nxt][bkr0][bnq0] = pb0;
      *(float4*)&Bs[nxt][bkr1][bnq1] = pb1;
    }
    __syncthreads();
  }

  float* __restrict__ dst = part + (size_t)kb * B_N * M_DIM;
#pragma unroll
  for (int j = 0; j < 4; ++j) {
    *(float4*)&dst[(size_t)(bm + tr * 4 + j) * M_DIM + bn + tc * 4] =
        make_float4(acc[j][0], acc[j][1], acc[j][2], acc[j][3]);
  }
}

// ---------------------------------------------------------------------------
// Kernel 2: phi row-panels + mu/count. feat = relu(p0+p1+p2+p3) in staging.
// grid = (17, C): panels 0..15 -> 32 rows x 512 cols; panel 16 -> mu/count.
// 256 thr, chunk=8 (LDS 16 KB -> more co-resident blocks). Regular L2-routed
// float4 stores (1 KB dense per wave-instr).
// ---------------------------------------------------------------------------
__global__ __launch_bounds__(256, 4) void phi_mu_kernel(
    const float* __restrict__ p0, const float* __restrict__ p1,
    const float* __restrict__ p2, const float* __restrict__ p3,
    const int* __restrict__ counts, const int* __restrict__ idx,
    float* __restrict__ phi, float* __restrict__ mu,
    float* __restrict__ cnt_out) {
  const int c = blockIdx.y;
  const int n = counts[c];
  const int* __restrict__ id = idx + c * B_N;
  const int t = threadIdx.x;

  if (blockIdx.x == 16) {  // ---- mu / count path ----
    float2 acc = make_float2(0.f, 0.f);
    for (int s = 0; s < n; ++s) {
      const size_t o = (size_t)id[s] * M_DIM + t * 2;
      const float2 q0 = *(const float2*)&p0[o];
      const float2 q1 = *(const float2*)&p1[o];
      const float2 q2 = *(const float2*)&p2[o];
      const float2 q3 = *(const float2*)&p3[o];
      acc.x += fmaxf(((q0.x + q1.x) + q2.x) + q3.x, 0.f);
      acc.y += fmaxf(((q0.y + q1.y) + q2.y) + q3.y, 0.f);
    }
    *(float2*)&mu[(size_t)c * M_DIM + t * 2] = acc;
    if (t == 0) cnt_out[c] = (float)n;
    return;
  }

  // ---- phi row-panel path: rows 32*px..+32, all 512 cols ----
  const int px = (int)blockIdx.x;      // 0..15
  const int tr = t >> 6;               // row group 0..3 (x8 rows)
  const int tc = t & 63;               // cols tc*4 and 256+tc*4

  __shared__ float F[8][M_DIM];        // 16 KB

  float acc[8][8] = {};  // [r][q]: q<4 -> col tc*4+q ; q>=4 -> 256+tc*4+q-4

  for (int s0 = 0; s0 < n; s0 += 8) {
    const int chunk  = min(8, n - s0);
    if (s0) __syncthreads();           // protect F before overwrite
    const int nslots = chunk << 7;     // chunk * 128 float4 per row
    for (int v = t; v < nslots; v += 256) {
      const int sl   = v >> 7;
      const int fp   = (v & 127) << 2;
      const size_t o = (size_t)id[s0 + sl] * M_DIM + fp;
      const float4 q0 = *(const float4*)&p0[o];
      const float4 q1 = *(const float4*)&p1[o];
      const float4 q2 = *(const float4*)&p2[o];
      const float4 q3 = *(const float4*)&p3[o];
      float4 f;
      f.x = fmaxf(((q0.x + q1.x) + q2.x) + q3.x, 0.f);
      f.y = fmaxf(((q0.y + q1.y) + q2.y) + q3.y, 0.f);
      f.z = fmaxf(((q0.z + q1.z) + q2.z) + q3.z, 0.f);
      f.w = fmaxf(((q0.w + q1.w) + q2.w) + q3.w, 0.f);
      *(float4*)&F[sl][fp] = f;
    }
    __syncthreads();
    for (int sl = 0; sl < chunk; ++sl) {
      const float4 a0 = *(const float4*)&F[sl][px * 32 + tr * 8];      // bcast
      const float4 a1 = *(const float4*)&F[sl][px * 32 + tr * 8 + 4];  // bcast
      const float4 b0 = *(const float4*)&F[sl][tc * 4];        // contiguous
      const float4 b1 = *(const float4*)&F[sl][256 + tc * 4];  // contiguous
      const float av[8] = {a0.x, a0.y, a0.z, a0.w, a1.x, a1.y, a1.z, a1.w};
      const float bv[8] = {b0.x, b0.y, b0.z, b0.w, b1.x, b1.y, b1.z, b1.w};
#pragma unroll
      for (int r = 0; r < 8; ++r)
#pragma unroll
        for (int q = 0; q < 8; ++q)
          acc[r][q] += av[r] * bv[q];
    }
  }

  float* __restrict__ out = phi + (size_t)c * M_DIM * M_DIM;
#pragma unroll
  for (int r = 0; r < 8; ++r) {
    const size_t row = (size_t)(px * 32 + tr * 8 + r) * M_DIM;
    *(float4*)&out[row + tc * 4] =
        make_float4(acc[r][0], acc[r][1], acc[r][2], acc[r][3]);
    *(float4*)&out[row + 256 + tc * 4] =
        make_float4(acc[r][4], acc[r][5], acc[r][6], acc[r][7]);
  }
}

// ---------------------------------------------------------------------------
extern "C" void kernel_launch(void* const* d_in, const int* in_sizes, int n_in,
                              void* d_out, int out_size, void* d_ws,
                              size_t ws_size, hipStream_t stream) {
  const float* X      = (const float*)d_in[0];
  const float* W      = (const float*)d_in[1];
  const int*   labels = (const int*)d_in[2];

  float* out = (float*)d_out;
  float* phi = out;                                // C*M*M
  float* mu  = out + (size_t)C_N * M_DIM * M_DIM;  // C*M
  float* cnt = mu + (size_t)C_N * M_DIM;           // C

  float* part   = (float*)d_ws;                    // 4 x B*M fp32 = 8 MB
  int*   counts = (int*)((char*)d_ws +
                         (size_t)KSPLIT * B_N * M_DIM * sizeof(float));
  int*   idx    = counts + 128;                    // C*B ints

  const size_t seg = (size_t)B_N * M_DIM;

  hipLaunchKernelGGL(gemm_index_kernel, dim3(NGEMM + NIDX), dim3(256), 0,
                     stream, X, W, labels, part, counts, idx);
  hipLaunchKernelGGL(phi_mu_kernel, dim3(17, C_N), dim3(256), 0, stream,
                     part, part + seg, part + 2 * seg, part + 3 * seg,
                     counts, idx, phi, mu, cnt);
}